// Round 1
// 191.710 us; speedup vs baseline: 1.0540x; 1.0540x over previous
//
#include <hip/hip_runtime.h>
#include <hip/hip_bf16.h>

typedef __bf16 bf16x8 __attribute__((ext_vector_type(8)));
typedef float f32x4 __attribute__((ext_vector_type(4)));
typedef unsigned int u32x4 __attribute__((ext_vector_type(4)));

#define QSCALE 0.18033688011112042f  /* 0.125 * log2(e) */

__device__ __forceinline__ void gload16(const void* g, void* l) {
  __builtin_amdgcn_global_load_lds(
      (const __attribute__((address_space(1))) uint32_t*)g,
      (__attribute__((address_space(3))) uint32_t*)l, 16, 0, 0);
}

__device__ __forceinline__ unsigned bf16bits(float f) {
  union { __bf16 h; unsigned short u; } c; c.h = (__bf16)f; return c.u;
}

// raw v_exp_f32: D = 2^x. Exact semantics we need (|x| small); skips OCML fixup.
__device__ __forceinline__ float exp2_raw(float x) {
  float r;
  asm("v_exp_f32 %0, %1" : "=v"(r) : "v"(x));
  return r;
}

// packed f32x2 -> bf16x2 in one reg (lo = a, hi = b)
__device__ __forceinline__ unsigned cvt_pk_bf16(float a, float b) {
  unsigned r;
  asm("v_cvt_pk_bf16_f32 %0, %1, %2" : "=v"(r) : "v"(a), "v"(b));
  return r;
}

// gfx950 cross-lane half swaps: SWAPL32 exchanges hi-32-lanes of a with
// lo-32-lanes of b; SWAPL16 exchanges odd-16-lane rows of a with even rows of b.
#define SWAPL32(a, b) asm("v_permlane32_swap_b32 %0, %1" : "+v"(a), "+v"(b))
#define SWAPL16(a, b) asm("v_permlane16_swap_b32 %0, %1" : "+v"(a), "+v"(b))

// ---------------------------------------------------------------- fused fp32 -> bf16 casts
// blocks [0,4096): x ; then 512 blocks per weight (wq,wk,wv,wo)
__global__ __launch_bounds__(256) void cast_all(
    const float* __restrict__ x, const float* __restrict__ wq, const float* __restrict__ wk,
    const float* __restrict__ wv, const float* __restrict__ wo,
    __bf16* __restrict__ xbf, __bf16* __restrict__ wqb, __bf16* __restrict__ wkb,
    __bf16* __restrict__ wvb, __bf16* __restrict__ wob) {
  int b = blockIdx.x;
  const float* src;
  __bf16* dst;
  int i;
  if (b < 4096) {
    src = x; dst = xbf; i = b * 256 + threadIdx.x;
  } else {
    int s = (b - 4096) >> 9;
    i = ((b - 4096) & 511) * 256 + threadIdx.x;
    src = (s == 0) ? wq : (s == 1) ? wk : (s == 2) ? wv : wo;
    dst = (s == 0) ? wqb : (s == 1) ? wkb : (s == 2) ? wvb : wob;
  }
  const float4* p = (const float4*)src;
  float4 a = p[2 * i], c = p[2 * i + 1];
  bf16x8 v;
  v[0] = (__bf16)a.x; v[1] = (__bf16)a.y; v[2] = (__bf16)a.z; v[3] = (__bf16)a.w;
  v[4] = (__bf16)c.x; v[5] = (__bf16)c.y; v[6] = (__bf16)c.z; v[7] = (__bf16)c.w;
  ((bf16x8*)dst)[i] = v;
}

// ---------------------------------------------------------------- NT GEMM  Y = A @ W^T + b
// m97-pattern staging (R12/R13-verified, BK=32): global_load_lds(16B) into linear
// [128][32] LDS tiles. MODE 0: sel=0 -> Q ([B,H,N,64], scaled), sel=1 -> K,
// sel=2 -> Vt ([B,H,64,N], vectorized transposed store). MODE 1: fp32 output.
template <int MODE>
__global__ __launch_bounds__(256) void gemm_nt(
    const __bf16* __restrict__ A,
    const __bf16* __restrict__ W0, const __bf16* __restrict__ W1, const __bf16* __restrict__ W2,
    const float* __restrict__ b0, const float* __restrict__ b1, const float* __restrict__ b2,
    __bf16* __restrict__ o0, __bf16* __restrict__ o1, __bf16* __restrict__ o2,
    float* __restrict__ of) {
  __shared__ __bf16 lA[128 * 32];
  __shared__ __bf16 lB[128 * 32];
  const int t = threadIdx.x;
  const int lane = t & 63;
  const int w = t >> 6;
  const int wr = w >> 1, wc = w & 1;
  const int l16 = lane & 15, l4 = lane >> 4;
  const int m0 = blockIdx.x * 128;
  int sel, bn;
  if (MODE == 0) { sel = blockIdx.y >> 3; bn = (blockIdx.y & 7) * 128; }
  else           { sel = 0;               bn = blockIdx.y * 128; }
  const __bf16* W   = (sel == 0) ? W0 : (sel == 1) ? W1 : W2;
  const float* bias = (sel == 0) ? b0 : (sel == 1) ? b1 : b2;

  f32x4 acc[4][4] = {};

  for (int k0 = 0; k0 < 1024; k0 += 32) {
    __syncthreads();
#pragma unroll
    for (int i = 0; i < 2; i++) {
      int c = t + i * 256;               // chunk 0..511
      int r = c >> 2, cp = c & 3;        // row, 16B-chunk within row
      gload16(A + (size_t)(m0 + r) * 1024 + k0 + cp * 8, lA + c * 8);
      gload16(W + (size_t)(bn + r) * 1024 + k0 + cp * 8, lB + c * 8);
    }
    __syncthreads();
    bf16x8 af[4], bfr[4];
#pragma unroll
    for (int m = 0; m < 4; m++)
      af[m] = *(const bf16x8*)(lA + (wr * 64 + m * 16 + l16) * 32 + l4 * 8);
#pragma unroll
    for (int n = 0; n < 4; n++)
      bfr[n] = *(const bf16x8*)(lB + (wc * 64 + n * 16 + l16) * 32 + l4 * 8);
#pragma unroll
    for (int m = 0; m < 4; m++)
#pragma unroll
      for (int n = 0; n < 4; n++)
        acc[m][n] = __builtin_amdgcn_mfma_f32_16x16x32_bf16(af[m], bfr[n], acc[m][n], 0, 0, 0);
  }

  const float scl = (MODE == 0 && sel == 0) ? QSCALE : 1.0f;
  __bf16* outp = (sel == 0) ? o0 : (sel == 1) ? o1 : o2;
#pragma unroll
  for (int n = 0; n < 4; n++) {
    const int col = bn + wc * 64 + n * 16 + l16;
    const float bv = bias[col];
    if (MODE == 0 && sel == 2) {
      // Vt [B,H,64,N]: rows nn contiguous across (l4, j) -> 8B vector stores
      const int h = col >> 6, hc = col & 63;
#pragma unroll
      for (int m = 0; m < 4; m++) {
        const int nnb = m0 + wr * 64 + m * 16 + l4 * 4;
        const int b_ = nnb >> 11, nn = nnb & 2047;
        ushort4 ov;
        ov.x = (unsigned short)bf16bits(acc[m][n][0] + bv);
        ov.y = (unsigned short)bf16bits(acc[m][n][1] + bv);
        ov.z = (unsigned short)bf16bits(acc[m][n][2] + bv);
        ov.w = (unsigned short)bf16bits(acc[m][n][3] + bv);
        *(ushort4*)(outp + ((size_t)(b_ * 16 + h) * 64 + hc) * 2048 + nn) = ov;
      }
    } else {
#pragma unroll
      for (int m = 0; m < 4; m++) {
#pragma unroll
        for (int j = 0; j < 4; j++) {
          const int row = m0 + wr * 64 + m * 16 + l4 * 4 + j;
          float v = acc[m][n][j] + bv;
          if (MODE == 0) {
            v *= scl;
            int b_ = row >> 11, nn = row & 2047;
            int h = col >> 6, hc = col & 63;
            outp[(((size_t)(b_ * 16 + h)) * 2048 + nn) * 64 + hc] = (__bf16)v;
          } else {
            of[(size_t)row * 1024 + col] = v;
          }
        }
      }
    }
  }
}

// ---------------------------------------------------------------- flash attention
// R14: PV moved from half-rate 16x16x16 (K=16) to full-rate 16x16x32 MFMA.
// The K=32 B-frag (col=l16, k=l4*8+j) is built from the swapped-QK^T S^T regs
// (kv=l4*4+j per 16-block) by a 4-step lane-bit permutation:
//   2x v_permlane32_swap (reg-bit n <-> lane-bit5), then
//   2x v_permlane16_swap (reg-bit   <-> lane-bit4).
// Row-sums now come free via one extra mfma(ones, P) per (strip, 32-kv group)
// (all D rows identical = full K-sum per q-col), deleting ~32 VALU adds/tile
// and the final shfl_xor reduction. V-frags become 8x ds_read_b128 (contiguous
// kv octets match the K=32 A-frag layout). Everything else unchanged:
// swapped-operand no-max softmax, QBLK=128 (4 waves x 2 strips), chunk-major
// LDS, double-buffered gload16, raw v_exp_f32, s_setprio around MFMA clusters.
__global__ __launch_bounds__(256) void attn_fwd(const __bf16* __restrict__ Q,
                                                const __bf16* __restrict__ K,
                                                const __bf16* __restrict__ Vt,
                                                __bf16* __restrict__ O) {
  __shared__ __bf16 sm[16384];   // buf b: K at sm+b*4096, V at sm+8192+b*4096
  const int flat = blockIdx.x;                 // 1024 blocks, bijective XCD chunking
  const int wg = (flat & 7) * 128 + (flat >> 3);
  const int bh = wg >> 4;
  const int q0 = (wg & 15) * 128;
  const __bf16* Qh = Q + (size_t)bh * 2048 * 64;
  const __bf16* Kh = K + (size_t)bh * 2048 * 64;
  const __bf16* Vh = Vt + (size_t)bh * 64 * 2048;
  const int t = threadIdx.x, lane = t & 63, w = t >> 6;
  const int l16 = lane & 15, l4 = lane >> 4;

  // Q fragments: 2 strips of 16 q, live whole kernel
  bf16x8 qf[2][2];
#pragma unroll
  for (int st = 0; st < 2; st++)
#pragma unroll
    for (int kk = 0; kk < 2; kk++)
      qf[st][kk] = *(const bf16x8*)(Qh + (size_t)(q0 + w * 32 + st * 16 + l16) * 64 + kk * 32 + l4 * 8);

  f32x4 ao[2][4] = {};
  f32x4 rs4[2] = {};       // row-sum accumulators (via mfma(ones, P))
  bf16x8 onesf;
#pragma unroll
  for (int i = 0; i < 8; i++) onesf[i] = (__bf16)1.0f;

  // K frag-read base (elements): chunk l4, row l16
  const int rdbase = l4 * 512 + l16 * 8;
  // V frag-read base (elements) for K=32 A-operand: chunk (4g+l4), row c=cb*16+l16
  const int vb = 8192 + l4 * 512 + l16 * 8;

  // prologue: stage tile 0
#pragma unroll
  for (int i = 0; i < 2; i++) {
    int ic = w * 2 + i;
    gload16(Kh + (size_t)lane * 64 + ic * 8, sm + ic * 512 + lane * 8);
    gload16(Vh + (size_t)lane * 2048 + ic * 8, sm + 8192 + ic * 512 + lane * 8);
  }
  __syncthreads();

#define ATTN_STEP(CUR, TNEXT)                                                         \
  {                                                                                   \
    const __bf16* lds = sm + (CUR) * 4096;                                            \
    if ((TNEXT) < 32) {                                                               \
      const int kvn = (TNEXT) * 64;                                                   \
      __bf16* dst = sm + ((CUR) ^ 1) * 4096;                                          \
      _Pragma("unroll")                                                               \
      for (int i = 0; i < 2; i++) {                                                   \
        int ic = w * 2 + i;                                                           \
        gload16(Kh + (size_t)(kvn + lane) * 64 + ic * 8, dst + ic * 512 + lane * 8);  \
        gload16(Vh + (size_t)lane * 2048 + kvn + ic * 8, dst + 8192 + ic * 512 + lane * 8); \
      }                                                                               \
    }                                                                                 \
    f32x4 s[2][4] = {};                                                               \
    __builtin_amdgcn_s_setprio(1);                                                    \
    _Pragma("unroll")                                                                 \
    for (int kk = 0; kk < 2; kk++) {                                                  \
      _Pragma("unroll")                                                               \
      for (int n = 0; n < 4; n++) {                                                   \
        bf16x8 kf = *(const bf16x8*)(lds + rdbase + kk * 2048 + n * 128);             \
        _Pragma("unroll")                                                             \
        for (int st = 0; st < 2; st++)                                                \
          s[st][n] = __builtin_amdgcn_mfma_f32_16x16x32_bf16(kf, qf[st][kk], s[st][n], 0, 0, 0); \
      }                                                                               \
    }                                                                                 \
    __builtin_amdgcn_s_setprio(0);                                                    \
    bf16x8 vf[2][4];                                                                  \
    _Pragma("unroll")                                                                 \
    for (int g = 0; g < 2; g++)                                                       \
      _Pragma("unroll")                                                               \
      for (int cb = 0; cb < 4; cb++)                                                  \
        vf[g][cb] = *(const bf16x8*)(lds + vb + g * 2048 + cb * 128);                 \
    u32x4 pk[2][2];                                                                   \
    _Pragma("unroll")                                                                 \
    for (int st = 0; st < 2; st++) {                                                  \
      _Pragma("unroll")                                                               \
      for (int g = 0; g < 2; g++) {                                                   \
        float p0 = exp2_raw(s[st][2 * g][0]),     p1 = exp2_raw(s[st][2 * g][1]);     \
        float p2 = exp2_raw(s[st][2 * g][2]),     p3 = exp2_raw(s[st][2 * g][3]);     \
        float p4 = exp2_raw(s[st][2 * g + 1][0]), p5 = exp2_raw(s[st][2 * g + 1][1]); \
        float p6 = exp2_raw(s[st][2 * g + 1][2]), p7 = exp2_raw(s[st][2 * g + 1][3]); \
        unsigned c00 = cvt_pk_bf16(p0, p1), c01 = cvt_pk_bf16(p2, p3);                \
        unsigned c10 = cvt_pk_bf16(p4, p5), c11 = cvt_pk_bf16(p6, p7);                \
        SWAPL32(c00, c10); SWAPL32(c01, c11);                                         \
        SWAPL16(c00, c10); SWAPL16(c01, c11);                                         \
        u32x4 tv = {c00, c01, c10, c11};                                              \
        pk[st][g] = tv;                                                               \
      }                                                                               \
    }                                                                                 \
    __builtin_amdgcn_s_setprio(1);                                                    \
    _Pragma("unroll")                                                                 \
    for (int st = 0; st < 2; st++) {                                                  \
      _Pragma("unroll")                                                               \
      for (int g = 0; g < 2; g++) {                                                   \
        union { u32x4 u; bf16x8 h; } cv; cv.u = pk[st][g];                            \
        rs4[st] = __builtin_amdgcn_mfma_f32_16x16x32_bf16(onesf, cv.h, rs4[st], 0, 0, 0); \
        _Pragma("unroll")                                                             \
        for (int cb = 0; cb < 4; cb++)                                                \
          ao[st][cb] = __builtin_amdgcn_mfma_f32_16x16x32_bf16(vf[g][cb], cv.h, ao[st][cb], 0, 0, 0); \
      }                                                                               \
    }                                                                                 \
    __builtin_amdgcn_s_setprio(0);                                                    \
    __syncthreads();                                                                  \
  }

  for (int tkv = 0; tkv < 32; tkv += 2) {
    ATTN_STEP(0, tkv + 1);
    ATTN_STEP(1, tkv + 2);
  }
#undef ATTN_STEP

  // rs4[st] regs are the full row-sum for q = l16 of strip st (all l4 identical)
  const int b_ = bh >> 4, h = bh & 15;
#pragma unroll
  for (int st = 0; st < 2; st++) {
    const float inv = 1.f / rs4[st][0];
    const int qrow = q0 + w * 32 + st * 16 + l16;
#pragma unroll
    for (int cb = 0; cb < 4; cb++) {
      ushort4 ov;
      ov.x = (unsigned short)bf16bits(ao[st][cb][0] * inv);
      ov.y = (unsigned short)bf16bits(ao[st][cb][1] * inv);
      ov.z = (unsigned short)bf16bits(ao[st][cb][2] * inv);
      ov.w = (unsigned short)bf16bits(ao[st][cb][3] * inv);
      *(ushort4*)(O + ((size_t)b_ * 2048 + qrow) * 1024 + h * 64 + cb * 16 + l4 * 4) = ov;
    }
  }
}

// ---------------------------------------------------------------- launch
extern "C" void kernel_launch(void* const* d_in, const int* in_sizes, int n_in,
                              void* d_out, int out_size, void* d_ws, size_t ws_size,
                              hipStream_t stream) {
  const float* x  = (const float*)d_in[0];
  const float* wq = (const float*)d_in[1];
  const float* bq = (const float*)d_in[2];
  const float* wk = (const float*)d_in[3];
  const float* bk = (const float*)d_in[4];
  const float* wv = (const float*)d_in[5];
  const float* bv = (const float*)d_in[6];
  const float* wo = (const float*)d_in[7];
  const float* bo = (const float*)d_in[8];
  float* out = (float*)d_out;

  const size_t NX = 8388608;   // 8192*1024
  const size_t NW = 1048576;   // 1024*1024
  __bf16* xbf = (__bf16*)d_ws;       // also reused as attention output O
  __bf16* wqb = xbf + NX;
  __bf16* wkb = wqb + NW;
  __bf16* wvb = wkb + NW;
  __bf16* wob = wvb + NW;
  __bf16* Qb  = wob + NW;
  __bf16* Kb  = Qb + NX;
  __bf16* Vtb = Kb + NX;

  cast_all<<<6144, 256, 0, stream>>>(x, wq, wk, wv, wo, xbf, wqb, wkb, wvb, wob);

  gemm_nt<0><<<dim3(64, 24), 256, 0, stream>>>(xbf, wqb, wkb, wvb, bq, bk, bv,
                                               Qb, Kb, Vtb, nullptr);
  attn_fwd<<<1024, 256, 0, stream>>>(Qb, Kb, Vtb, xbf /* O */);
  gemm_nt<1><<<dim3(64, 8), 256, 0, stream>>>(xbf, wob, nullptr, nullptr, bo, nullptr, nullptr,
                                              nullptr, nullptr, nullptr, out);
}

// Round 2
// 184.978 us; speedup vs baseline: 1.0923x; 1.0364x over previous
//
#include <hip/hip_runtime.h>
#include <hip/hip_bf16.h>

typedef __bf16 bf16x8 __attribute__((ext_vector_type(8)));
typedef float f32x4 __attribute__((ext_vector_type(4)));
typedef unsigned int u32x4 __attribute__((ext_vector_type(4)));

#define QSCALE 0.18033688011112042f  /* 0.125 * log2(e) */

__device__ __forceinline__ void gload16(const void* g, void* l) {
  __builtin_amdgcn_global_load_lds(
      (const __attribute__((address_space(1))) uint32_t*)g,
      (__attribute__((address_space(3))) uint32_t*)l, 16, 0, 0);
}

__device__ __forceinline__ unsigned bf16bits(float f) {
  union { __bf16 h; unsigned short u; } c; c.h = (__bf16)f; return c.u;
}

// raw v_exp_f32: D = 2^x. Exact semantics we need (|x| small); skips OCML fixup.
__device__ __forceinline__ float exp2_raw(float x) {
  float r;
  asm("v_exp_f32 %0, %1" : "=v"(r) : "v"(x));
  return r;
}

// packed f32x2 -> bf16x2 in one reg (lo = a, hi = b)
__device__ __forceinline__ unsigned cvt_pk_bf16(float a, float b) {
  unsigned r;
  asm("v_cvt_pk_bf16_f32 %0, %1, %2" : "=v"(r) : "v"(a), "v"(b));
  return r;
}

// gfx950 cross-lane half swaps: SWAPL32 exchanges hi-32-lanes of a with
// lo-32-lanes of b; SWAPL16 exchanges odd-16-lane rows of a with even rows of b.
#define SWAPL32(a, b) asm("v_permlane32_swap_b32 %0, %1" : "+v"(a), "+v"(b))
#define SWAPL16(a, b) asm("v_permlane16_swap_b32 %0, %1" : "+v"(a), "+v"(b))

// ---------------------------------------------------------------- fused fp32 -> bf16 casts
// blocks [0,4096): x ; then 512 blocks per weight (wq,wk,wv,wo)
__global__ __launch_bounds__(256) void cast_all(
    const float* __restrict__ x, const float* __restrict__ wq, const float* __restrict__ wk,
    const float* __restrict__ wv, const float* __restrict__ wo,
    __bf16* __restrict__ xbf, __bf16* __restrict__ wqb, __bf16* __restrict__ wkb,
    __bf16* __restrict__ wvb, __bf16* __restrict__ wob) {
  int b = blockIdx.x;
  const float* src;
  __bf16* dst;
  int i;
  if (b < 4096) {
    src = x; dst = xbf; i = b * 256 + threadIdx.x;
  } else {
    int s = (b - 4096) >> 9;
    i = ((b - 4096) & 511) * 256 + threadIdx.x;
    src = (s == 0) ? wq : (s == 1) ? wk : (s == 2) ? wv : wo;
    dst = (s == 0) ? wqb : (s == 1) ? wkb : (s == 2) ? wvb : wob;
  }
  const float4* p = (const float4*)src;
  float4 a = p[2 * i], c = p[2 * i + 1];
  bf16x8 v;
  v[0] = (__bf16)a.x; v[1] = (__bf16)a.y; v[2] = (__bf16)a.z; v[3] = (__bf16)a.w;
  v[4] = (__bf16)c.x; v[5] = (__bf16)c.y; v[6] = (__bf16)c.z; v[7] = (__bf16)c.w;
  ((bf16x8*)dst)[i] = v;
}

// ---------------------------------------------------------------- NT GEMM  Y = A @ W^T + b
// m97-pattern staging (R12/R13-verified, BK=32): global_load_lds(16B) into linear
// [128][32] LDS tiles. MODE 0: sel=0 -> Q ([B,H,N,64], scaled), sel=1 -> K,
// sel=2 -> Vt ([B,H,64,N], vectorized transposed store). MODE 1: fp32 output.
template <int MODE>
__global__ __launch_bounds__(256) void gemm_nt(
    const __bf16* __restrict__ A,
    const __bf16* __restrict__ W0, const __bf16* __restrict__ W1, const __bf16* __restrict__ W2,
    const float* __restrict__ b0, const float* __restrict__ b1, const float* __restrict__ b2,
    __bf16* __restrict__ o0, __bf16* __restrict__ o1, __bf16* __restrict__ o2,
    float* __restrict__ of) {
  __shared__ __bf16 lA[128 * 32];
  __shared__ __bf16 lB[128 * 32];
  const int t = threadIdx.x;
  const int lane = t & 63;
  const int w = t >> 6;
  const int wr = w >> 1, wc = w & 1;
  const int l16 = lane & 15, l4 = lane >> 4;
  const int m0 = blockIdx.x * 128;
  int sel, bn;
  if (MODE == 0) { sel = blockIdx.y >> 3; bn = (blockIdx.y & 7) * 128; }
  else           { sel = 0;               bn = blockIdx.y * 128; }
  const __bf16* W   = (sel == 0) ? W0 : (sel == 1) ? W1 : W2;
  const float* bias = (sel == 0) ? b0 : (sel == 1) ? b1 : b2;

  f32x4 acc[4][4] = {};

  for (int k0 = 0; k0 < 1024; k0 += 32) {
    __syncthreads();
#pragma unroll
    for (int i = 0; i < 2; i++) {
      int c = t + i * 256;               // chunk 0..511
      int r = c >> 2, cp = c & 3;        // row, 16B-chunk within row
      gload16(A + (size_t)(m0 + r) * 1024 + k0 + cp * 8, lA + c * 8);
      gload16(W + (size_t)(bn + r) * 1024 + k0 + cp * 8, lB + c * 8);
    }
    __syncthreads();
    bf16x8 af[4], bfr[4];
#pragma unroll
    for (int m = 0; m < 4; m++)
      af[m] = *(const bf16x8*)(lA + (wr * 64 + m * 16 + l16) * 32 + l4 * 8);
#pragma unroll
    for (int n = 0; n < 4; n++)
      bfr[n] = *(const bf16x8*)(lB + (wc * 64 + n * 16 + l16) * 32 + l4 * 8);
#pragma unroll
    for (int m = 0; m < 4; m++)
#pragma unroll
      for (int n = 0; n < 4; n++)
        acc[m][n] = __builtin_amdgcn_mfma_f32_16x16x32_bf16(af[m], bfr[n], acc[m][n], 0, 0, 0);
  }

  const float scl = (MODE == 0 && sel == 0) ? QSCALE : 1.0f;
  __bf16* outp = (sel == 0) ? o0 : (sel == 1) ? o1 : o2;
#pragma unroll
  for (int n = 0; n < 4; n++) {
    const int col = bn + wc * 64 + n * 16 + l16;
    const float bv = bias[col];
    if (MODE == 0 && sel == 2) {
      // Vt [B,H,64,N]: rows nn contiguous across (l4, j) -> 8B vector stores
      const int h = col >> 6, hc = col & 63;
#pragma unroll
      for (int m = 0; m < 4; m++) {
        const int nnb = m0 + wr * 64 + m * 16 + l4 * 4;
        const int b_ = nnb >> 11, nn = nnb & 2047;
        ushort4 ov;
        ov.x = (unsigned short)bf16bits(acc[m][n][0] + bv);
        ov.y = (unsigned short)bf16bits(acc[m][n][1] + bv);
        ov.z = (unsigned short)bf16bits(acc[m][n][2] + bv);
        ov.w = (unsigned short)bf16bits(acc[m][n][3] + bv);
        *(ushort4*)(outp + ((size_t)(b_ * 16 + h) * 64 + hc) * 2048 + nn) = ov;
      }
    } else {
#pragma unroll
      for (int m = 0; m < 4; m++) {
#pragma unroll
        for (int j = 0; j < 4; j++) {
          const int row = m0 + wr * 64 + m * 16 + l4 * 4 + j;
          float v = acc[m][n][j] + bv;
          if (MODE == 0) {
            v *= scl;
            int b_ = row >> 11, nn = row & 2047;
            int h = col >> 6, hc = col & 63;
            outp[(((size_t)(b_ * 16 + h)) * 2048 + nn) * 64 + hc] = (__bf16)v;
          } else {
            of[(size_t)row * 1024 + col] = v;
          }
        }
      }
    }
  }
}

// ---------------------------------------------------------------- flash attention
// R15: softmax/QK^T software pipeline (T15-style in-wave ILP). Per iteration t:
//   1. V(t) fragment ds_reads into regs (from buf t%2, staged 2 iters ago)
//   2. __syncthreads  (drains vmcnt -> tile t+1 staged by ALL waves; drains my
//      lgkm -> my V-frag reads done, so buf t%2 is safe to overwrite)
//   3. issue stage(t+2) -> buf t%2 (WAR-safe per step 2)
//   4. QK^T(t+1) MFMA interleaved 1:1 with softmax(t) VALU (exp/cvt/permlane) —
//      independent streams, co-issue on separate pipes within the wave
//   5. PV(t) MFMA (+ mfma(ones,P) row-sums)
// Score regs ping-pong sA/sB (static indexing via 2-step unroll, rule #20).
// Barrier count unchanged (1/iter); the vmcnt(0) drain at each barrier waits on
// loads issued a FULL iteration earlier (~600 cyc) -> nearly free. Everything
// else from R14 kept: full-rate K=32 PV, MFMA row-sums, swapped-operand no-max
// softmax, chunk-major LDS, raw v_exp_f32, s_setprio around compute.
__global__ __launch_bounds__(256) void attn_fwd(const __bf16* __restrict__ Q,
                                                const __bf16* __restrict__ K,
                                                const __bf16* __restrict__ Vt,
                                                __bf16* __restrict__ O) {
  __shared__ __bf16 sm[16384];   // buf b: K at sm+b*4096, V at sm+8192+b*4096
  const int flat = blockIdx.x;                 // 1024 blocks, bijective XCD chunking
  const int wg = (flat & 7) * 128 + (flat >> 3);
  const int bh = wg >> 4;
  const int q0 = (wg & 15) * 128;
  const __bf16* Qh = Q + (size_t)bh * 2048 * 64;
  const __bf16* Kh = K + (size_t)bh * 2048 * 64;
  const __bf16* Vh = Vt + (size_t)bh * 64 * 2048;
  const int t = threadIdx.x, lane = t & 63, w = t >> 6;
  const int l16 = lane & 15, l4 = lane >> 4;

  // Q fragments: 2 strips of 16 q, live whole kernel
  bf16x8 qf[2][2];
#pragma unroll
  for (int st = 0; st < 2; st++)
#pragma unroll
    for (int kk = 0; kk < 2; kk++)
      qf[st][kk] = *(const bf16x8*)(Qh + (size_t)(q0 + w * 32 + st * 16 + l16) * 64 + kk * 32 + l4 * 8);

  f32x4 ao[2][4] = {};
  f32x4 rs4[2] = {};       // row-sum accumulators (via mfma(ones, P))
  bf16x8 onesf;
#pragma unroll
  for (int i = 0; i < 8; i++) onesf[i] = (__bf16)1.0f;

  // K frag-read base (elements): chunk l4, row l16
  const int rdbase = l4 * 512 + l16 * 8;
  // V frag-read base (elements) for K=32 A-operand
  const int vb = 8192 + l4 * 512 + l16 * 8;

  f32x4 sA[2][4], sB[2][4];   // score ping-pong (tile t vs t+1)

  // prologue: stage tiles 0 (buf0) and 1 (buf1)
#pragma unroll
  for (int i = 0; i < 2; i++) {
    int ic = w * 2 + i;
    gload16(Kh + (size_t)lane * 64 + ic * 8,          sm + ic * 512 + lane * 8);
    gload16(Vh + (size_t)lane * 2048 + ic * 8,        sm + 8192 + ic * 512 + lane * 8);
    gload16(Kh + (size_t)(64 + lane) * 64 + ic * 8,   sm + 4096 + ic * 512 + lane * 8);
    gload16(Vh + (size_t)lane * 2048 + 64 + ic * 8,   sm + 12288 + ic * 512 + lane * 8);
  }
  __syncthreads();

// QK^T for one n-column of the next tile into SCUR (4 MFMA)
#define QK_N(KLDS, SCUR, n)                                                    \
  {                                                                            \
    bf16x8 kf0 = *(const bf16x8*)((KLDS) + rdbase + (n) * 128);                \
    bf16x8 kf1 = *(const bf16x8*)((KLDS) + rdbase + 2048 + (n) * 128);         \
    f32x4 z = {};                                                              \
    SCUR[0][(n)] = __builtin_amdgcn_mfma_f32_16x16x32_bf16(kf0, qf[0][0], z, 0, 0, 0); \
    SCUR[1][(n)] = __builtin_amdgcn_mfma_f32_16x16x32_bf16(kf0, qf[1][0], z, 0, 0, 0); \
    SCUR[0][(n)] = __builtin_amdgcn_mfma_f32_16x16x32_bf16(kf1, qf[0][1], SCUR[0][(n)], 0, 0, 0); \
    SCUR[1][(n)] = __builtin_amdgcn_mfma_f32_16x16x32_bf16(kf1, qf[1][1], SCUR[1][(n)], 0, 0, 0); \
  }

// softmax for one (st,g) group of the previous tile's scores -> pk[st][g]
#define SM_GROUP(SP, st_, g_)                                                  \
  {                                                                            \
    float p0 = exp2_raw(SP[(st_)][2 * (g_)][0]),     p1 = exp2_raw(SP[(st_)][2 * (g_)][1]); \
    float p2 = exp2_raw(SP[(st_)][2 * (g_)][2]),     p3 = exp2_raw(SP[(st_)][2 * (g_)][3]); \
    float p4 = exp2_raw(SP[(st_)][2 * (g_) + 1][0]), p5 = exp2_raw(SP[(st_)][2 * (g_) + 1][1]); \
    float p6 = exp2_raw(SP[(st_)][2 * (g_) + 1][2]), p7 = exp2_raw(SP[(st_)][2 * (g_) + 1][3]); \
    unsigned c00 = cvt_pk_bf16(p0, p1), c01 = cvt_pk_bf16(p2, p3);             \
    unsigned c10 = cvt_pk_bf16(p4, p5), c11 = cvt_pk_bf16(p6, p7);             \
    SWAPL32(c00, c10); SWAPL32(c01, c11);                                      \
    SWAPL16(c00, c10); SWAPL16(c01, c11);                                      \
    u32x4 tv = {c00, c01, c10, c11};                                           \
    pk[(st_)][(g_)] = tv;                                                      \
  }

#define ATTN_ITER(T, CUR, SPREV, SCUR)                                         \
  {                                                                            \
    const __bf16* vlds = sm + (CUR) * 4096;                                    \
    bf16x8 vf[2][4];                                                           \
    _Pragma("unroll")                                                          \
    for (int g = 0; g < 2; g++)                                                \
      _Pragma("unroll")                                                        \
      for (int cb = 0; cb < 4; cb++)                                           \
        vf[g][cb] = *(const bf16x8*)(vlds + vb + g * 2048 + cb * 128);         \
    __syncthreads();                                                           \
    if ((T) + 2 < 32) {                                                        \
      const int kvn = ((T) + 2) * 64;                                          \
      __bf16* dst = sm + (CUR) * 4096;                                         \
      _Pragma("unroll")                                                        \
      for (int i = 0; i < 2; i++) {                                            \
        int ic = w * 2 + i;                                                    \
        gload16(Kh + (size_t)(kvn + lane) * 64 + ic * 8, dst + ic * 512 + lane * 8); \
        gload16(Vh + (size_t)lane * 2048 + kvn + ic * 8, dst + 8192 + ic * 512 + lane * 8); \
      }                                                                        \
    }                                                                          \
    u32x4 pk[2][2];                                                            \
    __builtin_amdgcn_s_setprio(1);                                             \
    if ((T) + 1 < 32) {                                                        \
      const __bf16* klds = sm + ((CUR) ^ 1) * 4096;                            \
      _Pragma("unroll")                                                        \
      for (int n = 0; n < 4; n++) {                                            \
        QK_N(klds, SCUR, n);                                                   \
        SM_GROUP(SPREV, (n >> 1), (n & 1));                                    \
      }                                                                        \
    } else {                                                                   \
      _Pragma("unroll")                                                        \
      for (int n = 0; n < 4; n++) SM_GROUP(SPREV, (n >> 1), (n & 1));          \
    }                                                                          \
    _Pragma("unroll")                                                          \
    for (int st = 0; st < 2; st++)                                             \
      _Pragma("unroll")                                                        \
      for (int g = 0; g < 2; g++) {                                            \
        union { u32x4 u; bf16x8 h; } cv; cv.u = pk[st][g];                     \
        rs4[st] = __builtin_amdgcn_mfma_f32_16x16x32_bf16(onesf, cv.h, rs4[st], 0, 0, 0); \
        _Pragma("unroll")                                                      \
        for (int cb = 0; cb < 4; cb++)                                         \
          ao[st][cb] = __builtin_amdgcn_mfma_f32_16x16x32_bf16(vf[g][cb], cv.h, ao[st][cb], 0, 0, 0); \
      }                                                                        \
    __builtin_amdgcn_s_setprio(0);                                             \
  }

  // prologue QK(0) -> sA (from buf0)
#pragma unroll
  for (int n = 0; n < 4; n++) QK_N(sm, sA, n);

  for (int tkv = 0; tkv < 32; tkv += 2) {
    ATTN_ITER(tkv,     0, sA, sB);
    ATTN_ITER(tkv + 1, 1, sB, sA);
  }
#undef ATTN_ITER
#undef SM_GROUP
#undef QK_N

  // rs4[st] regs are the full row-sum for q = l16 of strip st (all l4 identical)
  const int b_ = bh >> 4, h = bh & 15;
#pragma unroll
  for (int st = 0; st < 2; st++) {
    const float inv = 1.f / rs4[st][0];
    const int qrow = q0 + w * 32 + st * 16 + l16;
#pragma unroll
    for (int cb = 0; cb < 4; cb++) {
      ushort4 ov;
      ov.x = (unsigned short)bf16bits(ao[st][cb][0] * inv);
      ov.y = (unsigned short)bf16bits(ao[st][cb][1] * inv);
      ov.z = (unsigned short)bf16bits(ao[st][cb][2] * inv);
      ov.w = (unsigned short)bf16bits(ao[st][cb][3] * inv);
      *(ushort4*)(O + ((size_t)b_ * 2048 + qrow) * 1024 + h * 64 + cb * 16 + l4 * 4) = ov;
    }
  }
}

// ---------------------------------------------------------------- launch
extern "C" void kernel_launch(void* const* d_in, const int* in_sizes, int n_in,
                              void* d_out, int out_size, void* d_ws, size_t ws_size,
                              hipStream_t stream) {
  const float* x  = (const float*)d_in[0];
  const float* wq = (const float*)d_in[1];
  const float* bq = (const float*)d_in[2];
  const float* wk = (const float*)d_in[3];
  const float* bk = (const float*)d_in[4];
  const float* wv = (const float*)d_in[5];
  const float* bv = (const float*)d_in[6];
  const float* wo = (const float*)d_in[7];
  const float* bo = (const float*)d_in[8];
  float* out = (float*)d_out;

  const size_t NX = 8388608;   // 8192*1024
  const size_t NW = 1048576;   // 1024*1024
  __bf16* xbf = (__bf16*)d_ws;       // also reused as attention output O
  __bf16* wqb = xbf + NX;
  __bf16* wkb = wqb + NW;
  __bf16* wvb = wkb + NW;
  __bf16* wob = wvb + NW;
  __bf16* Qb  = wob + NW;
  __bf16* Kb  = Qb + NX;
  __bf16* Vtb = Kb + NX;

  cast_all<<<6144, 256, 0, stream>>>(x, wq, wk, wv, wo, xbf, wqb, wkb, wvb, wob);

  gemm_nt<0><<<dim3(64, 24), 256, 0, stream>>>(xbf, wqb, wkb, wvb, bq, bk, bv,
                                               Qb, Kb, Vtb, nullptr);
  attn_fwd<<<1024, 256, 0, stream>>>(Qb, Kb, Vtb, xbf /* O */);
  gemm_nt<1><<<dim3(64, 8), 256, 0, stream>>>(xbf, wob, nullptr, nullptr, bo, nullptr, nullptr,
                                              nullptr, nullptr, nullptr, out);
}